// Round 1
// baseline (315.491 us; speedup 1.0000x reference)
//
#include <hip/hip_runtime.h>

#define B_SZ 4
#define LQ 4096
#define LKV 4096
#define DIN 256
#define DOUT 128
#define QBLK 64
#define KVBLK 64
#define NT (LKV / KVBLK)

typedef unsigned short u16;
typedef __attribute__((ext_vector_type(8))) short bf16x8;
typedef __attribute__((ext_vector_type(4))) float f32x4;

__device__ __forceinline__ u16 f2bf(float x) {
  unsigned u = __float_as_uint(x);
  u += 0x7fffu + ((u >> 16) & 1u);
  return (u16)(u >> 16);
}

__device__ __forceinline__ void gload_lds16(const u16* g, u16* l) {
  __builtin_amdgcn_global_load_lds(
      (__attribute__((address_space(1))) unsigned int*)g,
      (__attribute__((address_space(3))) unsigned int*)l, 16, 0, 0);
}

// ---------------- QKV projection (fp32 vector, writes bf16) ----------------
// grid: (16384/16, 3), block: 128.  which: 0=Q (pre-scaled), 1=K, 2=V^T
__global__ __launch_bounds__(128) void qkv_proj_kernel(
    const float* __restrict__ ligand, const float* __restrict__ pocket,
    const float* __restrict__ Wq, const float* __restrict__ bq,
    const float* __restrict__ Wk, const float* __restrict__ bk,
    const float* __restrict__ Wv, const float* __restrict__ bv,
    u16* __restrict__ Qb, u16* __restrict__ Kb, u16* __restrict__ Vt) {
  const int which = blockIdx.y;
  const int row0 = blockIdx.x * 16;
  const int col = threadIdx.x;
  const float* __restrict__ src = (which == 0) ? ligand : pocket;
  const float* __restrict__ W = (which == 0) ? Wq : (which == 1) ? Wk : Wv;
  const float* __restrict__ bias = (which == 0) ? bq : (which == 1) ? bk : bv;

  float acc[16];
#pragma unroll
  for (int r = 0; r < 16; ++r) acc[r] = 0.f;

  for (int k = 0; k < DIN; k += 4) {
    float w0 = W[(k + 0) * DOUT + col];
    float w1 = W[(k + 1) * DOUT + col];
    float w2 = W[(k + 2) * DOUT + col];
    float w3 = W[(k + 3) * DOUT + col];
#pragma unroll
    for (int r = 0; r < 16; ++r) {
      const float4 x = *(const float4*)(src + (size_t)(row0 + r) * DIN + k);
      acc[r] = fmaf(x.x, w0, acc[r]);
      acc[r] = fmaf(x.y, w1, acc[r]);
      acc[r] = fmaf(x.z, w2, acc[r]);
      acc[r] = fmaf(x.w, w3, acc[r]);
    }
  }
  const float b = bias[col];
  if (which == 0) {
#pragma unroll
    for (int r = 0; r < 16; ++r)
      Qb[(size_t)(row0 + r) * DOUT + col] =
          f2bf((acc[r] + b) * 0.08838834764831845f);  // fold 1/sqrt(128)
  } else if (which == 1) {
#pragma unroll
    for (int r = 0; r < 16; ++r)
      Kb[(size_t)(row0 + r) * DOUT + col] = f2bf(acc[r] + b);
  } else {
    const int batch = row0 >> 12;
    const int kv0 = row0 & 4095;
    u16 tmp[16];
#pragma unroll
    for (int r = 0; r < 16; ++r) tmp[r] = f2bf(acc[r] + b);
    u16* dst = Vt + ((size_t)batch * DOUT + col) * LKV + kv0;
    *(uint4*)(dst) = *(const uint4*)(tmp);
    *(uint4*)(dst + 8) = *(const uint4*)(tmp + 8);
  }
}

// ---------------- Flash attention (bf16 MFMA 16x16x32) ----------------
// grid: (LQ/QBLK, B), block 256 (4 waves x 16 q-rows each)
__device__ __forceinline__ void stage_tiles(u16* KsB, u16* VsB,
                                            const u16* KbB, const u16* VtB,
                                            int t, int tid) {
  // K tile [64][128] bf16: 1024 x 16B chunks; LDS linear, global pre-swizzled
#pragma unroll
  for (int i = 0; i < 4; ++i) {
    const int c = i * 256 + tid;
    const int r = c >> 4, ch = c & 15;
    const int chg = ch ^ (r & 7);
    gload_lds16(KbB + (size_t)(t * KVBLK + r) * 128 + chg * 8, KsB + (size_t)c * 8);
  }
  // V^T tile [128][64] bf16
#pragma unroll
  for (int i = 0; i < 4; ++i) {
    const int c = i * 256 + tid;
    const int d = c >> 3, ch = c & 7;
    const int chg = ch ^ (d & 7);
    gload_lds16(VtB + (size_t)d * LKV + (size_t)t * KVBLK + chg * 8,
                VsB + (size_t)c * 8);
  }
}

__global__ __launch_bounds__(256) void flash_attn_kernel(
    const u16* __restrict__ Qb, const u16* __restrict__ Kb,
    const u16* __restrict__ Vt, float* __restrict__ attnO) {
  __shared__ __align__(16) u16 Ks[2][KVBLK * 128];
  __shared__ __align__(16) u16 Vs[2][128 * KVBLK];
  __shared__ __align__(16) u16 Ps[4][16 * 72];  // per-wave P, stride 72 (16B-aligned rows)

  const int batch = blockIdx.y;
  const int q0 = blockIdx.x * QBLK;
  const int tid = threadIdx.x;
  const int wid = tid >> 6;
  const int lane = tid & 63;
  const int lg = lane >> 4;  // lane group 0..3
  const int lr = lane & 15;  // 0..15

  const u16* Qw = Qb + ((size_t)batch * LQ + q0 + wid * 16) * 128;
  const u16* KbB = Kb + (size_t)batch * LKV * 128;
  const u16* VtB = Vt + (size_t)batch * 128 * LKV;

  // Q fragments: A-frag of mfma_16x16x32: lane holds Q[lr][ks*32 + lg*8 .. +8]
  bf16x8 qf[4];
#pragma unroll
  for (int ks = 0; ks < 4; ++ks)
    qf[ks] = *(const bf16x8*)(Qw + (size_t)lr * 128 + ks * 32 + lg * 8);

  f32x4 oacc[8];
#pragma unroll
  for (int dt = 0; dt < 8; ++dt) oacc[dt] = (f32x4){0.f, 0.f, 0.f, 0.f};
  float m_run[4], l_run[4];
#pragma unroll
  for (int j = 0; j < 4; ++j) {
    m_run[j] = -1e30f;
    l_run[j] = 0.f;
  }

  stage_tiles(&Ks[0][0], &Vs[0][0], KbB, VtB, 0, tid);
  __syncthreads();

  int cur = 0;
  for (int t = 0; t < NT; ++t) {
    if (t + 1 < NT)
      stage_tiles(&Ks[cur ^ 1][0], &Vs[cur ^ 1][0], KbB, VtB, t + 1, tid);

    const u16* KsB = &Ks[cur][0];
    const u16* VsB = &Vs[cur][0];

    // S = Q K^T  (per wave: [16 q][64 kv]); C/D: lane holds S[lg*4+j][ct*16+lr]
    f32x4 sacc[4];
#pragma unroll
    for (int ct = 0; ct < 4; ++ct) sacc[ct] = (f32x4){0.f, 0.f, 0.f, 0.f};
#pragma unroll
    for (int ks = 0; ks < 4; ++ks) {
#pragma unroll
      for (int ct = 0; ct < 4; ++ct) {
        const int r = ct * 16 + lr;
        const int ch = (ks * 4 + lg) ^ (r & 7);
        bf16x8 kf = *(const bf16x8*)(KsB + ((size_t)r * 16 + ch) * 8);
        sacc[ct] =
            __builtin_amdgcn_mfma_f32_16x16x32_bf16(qf[ks], kf, sacc[ct], 0, 0, 0);
      }
    }

    // online softmax (rows distributed: lane holds rows lg*4+j, cols lr of each ct)
    float pv[4][4];
    float corr[4];
#pragma unroll
    for (int j = 0; j < 4; ++j) {
      float mx = fmaxf(fmaxf(sacc[0][j], sacc[1][j]), fmaxf(sacc[2][j], sacc[3][j]));
#pragma unroll
      for (int s = 8; s >= 1; s >>= 1) mx = fmaxf(mx, __shfl_xor(mx, s, 64));
      const float mn = fmaxf(m_run[j], mx);
      corr[j] = __expf(m_run[j] - mn);
      m_run[j] = mn;
      float rs = 0.f;
#pragma unroll
      for (int ct = 0; ct < 4; ++ct) {
        const float p = __expf(sacc[ct][j] - mn);
        pv[ct][j] = p;
        rs += p;
      }
#pragma unroll
      for (int s = 8; s >= 1; s >>= 1) rs += __shfl_xor(rs, s, 64);
      l_run[j] = l_run[j] * corr[j] + rs;
    }

    // write P (bf16) to per-wave LDS tile [16 q][72]
#pragma unroll
    for (int ct = 0; ct < 4; ++ct)
#pragma unroll
      for (int j = 0; j < 4; ++j)
        Ps[wid][(lg * 4 + j) * 72 + ct * 16 + lr] = f2bf(pv[ct][j]);

    // rescale O
#pragma unroll
    for (int dt = 0; dt < 8; ++dt)
#pragma unroll
      for (int j = 0; j < 4; ++j) oacc[dt][j] *= corr[j];

    // O += P V  (A-frag P from LDS, B-frag from V^T tile)
#pragma unroll
    for (int ks2 = 0; ks2 < 2; ++ks2) {
      bf16x8 pf =
          *(const bf16x8*)(&Ps[wid][0] + (size_t)lr * 72 + ks2 * 32 + lg * 8);
#pragma unroll
      for (int dt = 0; dt < 8; ++dt) {
        const int d = dt * 16 + lr;
        const int ch = (ks2 * 4 + lg) ^ (d & 7);
        bf16x8 vf = *(const bf16x8*)(VsB + ((size_t)d * 8 + ch) * 8);
        oacc[dt] = __builtin_amdgcn_mfma_f32_16x16x32_bf16(pf, vf, oacc[dt], 0, 0, 0);
      }
    }
    __syncthreads();
    cur ^= 1;
  }

  float rl[4];
#pragma unroll
  for (int j = 0; j < 4; ++j) rl[j] = 1.f / l_run[j];
  float* O = attnO + ((size_t)batch * LQ + q0 + wid * 16) * 128;
#pragma unroll
  for (int dt = 0; dt < 8; ++dt)
#pragma unroll
    for (int j = 0; j < 4; ++j)
      O[(size_t)(lg * 4 + j) * 128 + dt * 16 + lr] = oacc[dt][j] * rl[j];
}

// ---------------- Output projection (fp32) ----------------
__global__ __launch_bounds__(128) void out_proj_kernel(
    const float* __restrict__ attnO, const float* __restrict__ Wo,
    const float* __restrict__ bo, float* __restrict__ out) {
  const int row0 = blockIdx.x * 16;
  const int col = threadIdx.x;
  float acc[16];
#pragma unroll
  for (int r = 0; r < 16; ++r) acc[r] = 0.f;
  for (int k = 0; k < DOUT; k += 4) {
    float w0 = Wo[(k + 0) * DOUT + col];
    float w1 = Wo[(k + 1) * DOUT + col];
    float w2 = Wo[(k + 2) * DOUT + col];
    float w3 = Wo[(k + 3) * DOUT + col];
#pragma unroll
    for (int r = 0; r < 16; ++r) {
      const float4 x = *(const float4*)(attnO + (size_t)(row0 + r) * DOUT + k);
      acc[r] = fmaf(x.x, w0, acc[r]);
      acc[r] = fmaf(x.y, w1, acc[r]);
      acc[r] = fmaf(x.z, w2, acc[r]);
      acc[r] = fmaf(x.w, w3, acc[r]);
    }
  }
  const float b = bo[col];
#pragma unroll
  for (int r = 0; r < 16; ++r)
    out[(size_t)(row0 + r) * DOUT + col] = acc[r] + b;
}

extern "C" void kernel_launch(void* const* d_in, const int* in_sizes, int n_in,
                              void* d_out, int out_size, void* d_ws,
                              size_t ws_size, hipStream_t stream) {
  const float* ligand = (const float*)d_in[0];
  const float* pocket = (const float*)d_in[1];
  const float* Wq = (const float*)d_in[2];
  const float* bq = (const float*)d_in[3];
  const float* Wk = (const float*)d_in[4];
  const float* bk = (const float*)d_in[5];
  const float* Wv = (const float*)d_in[6];
  const float* bv = (const float*)d_in[7];
  const float* Wo = (const float*)d_in[8];
  const float* bo = (const float*)d_in[9];
  float* out = (float*)d_out;

  char* ws = (char*)d_ws;
  u16* Qb = (u16*)(ws);                                   // 4 MB
  u16* Kb = (u16*)(ws + (size_t)4 * 1024 * 1024);         // 4 MB
  u16* Vt = (u16*)(ws + (size_t)8 * 1024 * 1024);         // 4 MB (V transposed)
  float* attnO = (float*)(ws + (size_t)12 * 1024 * 1024); // 8 MB

  dim3 g1((B_SZ * LQ) / 16, 3);
  qkv_proj_kernel<<<g1, dim3(128), 0, stream>>>(ligand, pocket, Wq, bq, Wk, bk,
                                                Wv, bv, Qb, Kb, Vt);
  dim3 g2(LQ / QBLK, B_SZ);
  flash_attn_kernel<<<g2, dim3(256), 0, stream>>>(Qb, Kb, Vt, attnO);
  dim3 g3((B_SZ * LQ) / 16);
  out_proj_kernel<<<g3, dim3(128), 0, stream>>>(attnO, Wo, bo, out);
}

// Round 2
// 186.467 us; speedup vs baseline: 1.6919x; 1.6919x over previous
//
#include <hip/hip_runtime.h>

#define B_SZ 4
#define LQ 4096
#define LKV 4096
#define DIN 256
#define DOUT 128
#define QBLK 64
#define KVBLK 64
#define NT (LKV / KVBLK)

typedef unsigned short u16;
typedef __attribute__((ext_vector_type(8))) short bf16x8;
typedef __attribute__((ext_vector_type(4))) float f32x4;

union Bf8Pack {
  u16 u[8];
  bf16x8 v;
};
union U16x4Pack {
  u16 u[4];
  uint2 v;
};

__device__ __forceinline__ u16 f2bf(float x) {
  unsigned u = __float_as_uint(x);
  u += 0x7fffu + ((u >> 16) & 1u);
  return (u16)(u >> 16);
}

__device__ __forceinline__ void gload_lds16(const u16* g, u16* l) {
  __builtin_amdgcn_global_load_lds(
      (__attribute__((address_space(1))) unsigned int*)g,
      (__attribute__((address_space(3))) unsigned int*)l, 16, 0, 0);
}

// ---------- weight transpose + bf16 convert: Wt[3][128][256], WoT[128][128] ----------
__global__ __launch_bounds__(256) void wtrans_kernel(
    const float* __restrict__ Wq, const float* __restrict__ Wk,
    const float* __restrict__ Wv, const float* __restrict__ Wo,
    u16* __restrict__ Wt, u16* __restrict__ WoT) {
  const int gid = blockIdx.x * 256 + threadIdx.x;
  if (gid < 3 * DOUT * DIN) {
    const int which = gid / (DOUT * DIN);
    const int r = gid % (DOUT * DIN);
    const int n = r >> 8;   // 0..127
    const int k = r & 255;  // 0..255
    const float* W = (which == 0) ? Wq : (which == 1) ? Wk : Wv;
    Wt[gid] = f2bf(W[k * DOUT + n]);
  } else {
    const int r = gid - 3 * DOUT * DIN;
    if (r < DOUT * DOUT) {
      const int n = r >> 7;
      const int k = r & 127;
      WoT[r] = f2bf(Wo[k * DOUT + n]);
    }
  }
}

// ---------- QKV projection via MFMA ----------
// grid (16384/64, 3), block 256 (4 waves x 16 src rows)
__global__ __launch_bounds__(256) void qkv_proj_mfma(
    const float* __restrict__ ligand, const float* __restrict__ pocket,
    const float* __restrict__ bq, const float* __restrict__ bk,
    const float* __restrict__ bv, const u16* __restrict__ Wt,
    u16* __restrict__ Qb, u16* __restrict__ Kb, u16* __restrict__ Vt) {
  const int which = blockIdx.y;
  const int row0 = blockIdx.x * 64;
  const int tid = threadIdx.x;
  const int wid = tid >> 6;
  const int lane = tid & 63;
  const int lg = lane >> 4, lr = lane & 15;
  const float* __restrict__ src = (which == 0) ? ligand : pocket;
  const int m = row0 + wid * 16 + lr;  // this lane's src row (frag row)

  // src fragments fp32 -> bf16 (lane holds src[m][ks*32+lg*8 .. +8])
  bf16x8 sfrag[8];
#pragma unroll
  for (int ks = 0; ks < 8; ++ks) {
    const float* p = src + (size_t)m * DIN + ks * 32 + lg * 8;
    const float4 a = *(const float4*)p;
    const float4 b = *(const float4*)(p + 4);
    Bf8Pack pk;
    pk.u[0] = f2bf(a.x); pk.u[1] = f2bf(a.y); pk.u[2] = f2bf(a.z); pk.u[3] = f2bf(a.w);
    pk.u[4] = f2bf(b.x); pk.u[5] = f2bf(b.y); pk.u[6] = f2bf(b.z); pk.u[7] = f2bf(b.w);
    sfrag[ks] = pk.v;
  }

  const u16* __restrict__ Wtw = Wt + (size_t)which * DOUT * DIN;

  if (which < 2) {
    // C[d][m] = Wt · src^T ; lane reg j holds d = dt*16+lg*4+j, m-col = lr
    const float* __restrict__ bias = (which == 0) ? bq : bk;
    u16* __restrict__ dst = (which == 0) ? Qb : Kb;
#pragma unroll
    for (int dt = 0; dt < 8; ++dt) {
      f32x4 acc = (f32x4){0.f, 0.f, 0.f, 0.f};
#pragma unroll
      for (int ks = 0; ks < 8; ++ks) {
        const bf16x8 wf =
            *(const bf16x8*)(Wtw + (size_t)(dt * 16 + lr) * DIN + ks * 32 + lg * 8);
        acc = __builtin_amdgcn_mfma_f32_16x16x32_bf16(wf, sfrag[ks], acc, 0, 0, 0);
      }
      U16x4Pack st;
#pragma unroll
      for (int j = 0; j < 4; ++j) {
        const int d = dt * 16 + lg * 4 + j;
        float v = acc[j] + bias[d];
        if (which == 0) v *= 0.08838834764831845f;  // fold 1/sqrt(128)
        st.u[j] = f2bf(v);
      }
      *(uint2*)(dst + (size_t)m * DOUT + dt * 16 + lg * 4) = st.v;
    }
  } else {
    // C[m][d] = src · Wv ; lane reg j holds kv = base+lg*4+j, d = dt*16+lr
    const int batch = row0 >> 12;
    const int kvbase = (row0 & 4095) + wid * 16 + lg * 4;
#pragma unroll
    for (int dt = 0; dt < 8; ++dt) {
      f32x4 acc = (f32x4){0.f, 0.f, 0.f, 0.f};
#pragma unroll
      for (int ks = 0; ks < 8; ++ks) {
        const bf16x8 wf =
            *(const bf16x8*)(Wtw + (size_t)(dt * 16 + lr) * DIN + ks * 32 + lg * 8);
        acc = __builtin_amdgcn_mfma_f32_16x16x32_bf16(sfrag[ks], wf, acc, 0, 0, 0);
      }
      const int d = dt * 16 + lr;
      const float b = bv[d];
      U16x4Pack st;
#pragma unroll
      for (int j = 0; j < 4; ++j) st.u[j] = f2bf(acc[j] + b);
      *(uint2*)(Vt + ((size_t)batch * DOUT + d) * LKV + kvbase) = st.v;
    }
  }
}

// ---------------- Flash attention (bf16 MFMA 16x16x32) ----------------
__device__ __forceinline__ void stage_tiles(u16* KsB, u16* VsB,
                                            const u16* KbB, const u16* VtB,
                                            int t, int tid) {
#pragma unroll
  for (int i = 0; i < 4; ++i) {
    const int c = i * 256 + tid;
    const int r = c >> 4, ch = c & 15;
    const int chg = ch ^ (r & 7);
    gload_lds16(KbB + (size_t)(t * KVBLK + r) * 128 + chg * 8, KsB + (size_t)c * 8);
  }
#pragma unroll
  for (int i = 0; i < 4; ++i) {
    const int c = i * 256 + tid;
    const int d = c >> 3, ch = c & 7;
    const int chg = ch ^ (d & 7);
    gload_lds16(VtB + (size_t)d * LKV + (size_t)t * KVBLK + chg * 8,
                VsB + (size_t)c * 8);
  }
}

__global__ __launch_bounds__(256) void flash_attn_kernel(
    const u16* __restrict__ Qb, const u16* __restrict__ Kb,
    const u16* __restrict__ Vt, u16* __restrict__ attnO) {
  __shared__ __align__(16) u16 Ks[2][KVBLK * 128];
  __shared__ __align__(16) u16 Vs[2][128 * KVBLK];
  __shared__ __align__(16) u16 Ps[4][16 * 72];

  const int batch = blockIdx.y;
  const int q0 = blockIdx.x * QBLK;
  const int tid = threadIdx.x;
  const int wid = tid >> 6;
  const int lane = tid & 63;
  const int lg = lane >> 4;
  const int lr = lane & 15;

  const u16* Qw = Qb + ((size_t)batch * LQ + q0 + wid * 16) * 128;
  const u16* KbB = Kb + (size_t)batch * LKV * 128;
  const u16* VtB = Vt + (size_t)batch * 128 * LKV;

  bf16x8 qf[4];
#pragma unroll
  for (int ks = 0; ks < 4; ++ks)
    qf[ks] = *(const bf16x8*)(Qw + (size_t)lr * 128 + ks * 32 + lg * 8);

  f32x4 oacc[8];
#pragma unroll
  for (int dt = 0; dt < 8; ++dt) oacc[dt] = (f32x4){0.f, 0.f, 0.f, 0.f};
  float m_run[4], l_run[4];
#pragma unroll
  for (int j = 0; j < 4; ++j) {
    m_run[j] = -1e30f;
    l_run[j] = 0.f;
  }

  stage_tiles(&Ks[0][0], &Vs[0][0], KbB, VtB, 0, tid);
  __syncthreads();

  int cur = 0;
  for (int t = 0; t < NT; ++t) {
    if (t + 1 < NT)
      stage_tiles(&Ks[cur ^ 1][0], &Vs[cur ^ 1][0], KbB, VtB, t + 1, tid);

    const u16* KsB = &Ks[cur][0];
    const u16* VsB = &Vs[cur][0];

    f32x4 sacc[4];
#pragma unroll
    for (int ct = 0; ct < 4; ++ct) sacc[ct] = (f32x4){0.f, 0.f, 0.f, 0.f};
#pragma unroll
    for (int ks = 0; ks < 4; ++ks) {
#pragma unroll
      for (int ct = 0; ct < 4; ++ct) {
        const int r = ct * 16 + lr;
        const int ch = (ks * 4 + lg) ^ (r & 7);
        bf16x8 kf = *(const bf16x8*)(KsB + ((size_t)r * 16 + ch) * 8);
        sacc[ct] =
            __builtin_amdgcn_mfma_f32_16x16x32_bf16(qf[ks], kf, sacc[ct], 0, 0, 0);
      }
    }

    float pv[4][4];
    float corr[4];
#pragma unroll
    for (int j = 0; j < 4; ++j) {
      float mx = fmaxf(fmaxf(sacc[0][j], sacc[1][j]), fmaxf(sacc[2][j], sacc[3][j]));
#pragma unroll
      for (int s = 8; s >= 1; s >>= 1) mx = fmaxf(mx, __shfl_xor(mx, s, 64));
      const float mn = fmaxf(m_run[j], mx);
      corr[j] = __expf(m_run[j] - mn);
      m_run[j] = mn;
      float rs = 0.f;
#pragma unroll
      for (int ct = 0; ct < 4; ++ct) {
        const float p = __expf(sacc[ct][j] - mn);
        pv[ct][j] = p;
        rs += p;
      }
#pragma unroll
      for (int s = 8; s >= 1; s >>= 1) rs += __shfl_xor(rs, s, 64);
      l_run[j] = l_run[j] * corr[j] + rs;
    }

#pragma unroll
    for (int ct = 0; ct < 4; ++ct)
#pragma unroll
      for (int j = 0; j < 4; ++j)
        Ps[wid][(lg * 4 + j) * 72 + ct * 16 + lr] = f2bf(pv[ct][j]);

#pragma unroll
    for (int dt = 0; dt < 8; ++dt)
#pragma unroll
      for (int j = 0; j < 4; ++j) oacc[dt][j] *= corr[j];

#pragma unroll
    for (int ks2 = 0; ks2 < 2; ++ks2) {
      bf16x8 pf =
          *(const bf16x8*)(&Ps[wid][0] + (size_t)lr * 72 + ks2 * 32 + lg * 8);
#pragma unroll
      for (int dt = 0; dt < 8; ++dt) {
        const int d = dt * 16 + lr;
        const int ch = (ks2 * 4 + lg) ^ (d & 7);
        bf16x8 vf = *(const bf16x8*)(VsB + ((size_t)d * 8 + ch) * 8);
        oacc[dt] = __builtin_amdgcn_mfma_f32_16x16x32_bf16(pf, vf, oacc[dt], 0, 0, 0);
      }
    }
    __syncthreads();
    cur ^= 1;
  }

  float rl[4];
#pragma unroll
  for (int j = 0; j < 4; ++j) rl[j] = 1.f / l_run[j];
  u16* O = attnO + ((size_t)batch * LQ + q0 + wid * 16) * 128;
#pragma unroll
  for (int dt = 0; dt < 8; ++dt)
#pragma unroll
    for (int j = 0; j < 4; ++j)
      O[(size_t)(lg * 4 + j) * 128 + dt * 16 + lr] = f2bf(oacc[dt][j] * rl[j]);
}

// ---------- output projection via MFMA ----------
// grid 16384/64, block 256; C[d][m] = WoT · attnO^T
__global__ __launch_bounds__(256) void out_proj_mfma(
    const u16* __restrict__ attnO, const u16* __restrict__ WoT,
    const float* __restrict__ bo, float* __restrict__ out) {
  const int row0 = blockIdx.x * 64;
  const int tid = threadIdx.x;
  const int wid = tid >> 6;
  const int lane = tid & 63;
  const int lg = lane >> 4, lr = lane & 15;
  const int m = row0 + wid * 16 + lr;

  bf16x8 ofrag[4];
#pragma unroll
  for (int ks = 0; ks < 4; ++ks)
    ofrag[ks] = *(const bf16x8*)(attnO + (size_t)m * DOUT + ks * 32 + lg * 8);

#pragma unroll
  for (int dt = 0; dt < 8; ++dt) {
    f32x4 acc = (f32x4){0.f, 0.f, 0.f, 0.f};
#pragma unroll
    for (int ks = 0; ks < 4; ++ks) {
      const bf16x8 wf =
          *(const bf16x8*)(WoT + (size_t)(dt * 16 + lr) * DOUT + ks * 32 + lg * 8);
      acc = __builtin_amdgcn_mfma_f32_16x16x32_bf16(wf, ofrag[ks], acc, 0, 0, 0);
    }
    float4 o;
    o.x = acc[0] + bo[dt * 16 + lg * 4 + 0];
    o.y = acc[1] + bo[dt * 16 + lg * 4 + 1];
    o.z = acc[2] + bo[dt * 16 + lg * 4 + 2];
    o.w = acc[3] + bo[dt * 16 + lg * 4 + 3];
    *(float4*)(out + (size_t)m * DOUT + dt * 16 + lg * 4) = o;
  }
}

extern "C" void kernel_launch(void* const* d_in, const int* in_sizes, int n_in,
                              void* d_out, int out_size, void* d_ws,
                              size_t ws_size, hipStream_t stream) {
  const float* ligand = (const float*)d_in[0];
  const float* pocket = (const float*)d_in[1];
  const float* Wq = (const float*)d_in[2];
  const float* bq = (const float*)d_in[3];
  const float* Wk = (const float*)d_in[4];
  const float* bk = (const float*)d_in[5];
  const float* Wv = (const float*)d_in[6];
  const float* bv = (const float*)d_in[7];
  const float* Wo = (const float*)d_in[8];
  const float* bo = (const float*)d_in[9];
  float* out = (float*)d_out;

  char* ws = (char*)d_ws;
  u16* Qb = (u16*)(ws);                                    // 4 MB
  u16* Kb = (u16*)(ws + (size_t)4 * 1024 * 1024);          // 4 MB
  u16* Vt = (u16*)(ws + (size_t)8 * 1024 * 1024);          // 4 MB (V^T)
  u16* attnO = (u16*)(ws + (size_t)12 * 1024 * 1024);      // 4 MB (bf16)
  u16* Wt = (u16*)(ws + (size_t)16 * 1024 * 1024);         // 192 KB
  u16* WoT = (u16*)(ws + (size_t)16 * 1024 * 1024 + 256 * 1024);  // 32 KB

  wtrans_kernel<<<dim3(448), dim3(256), 0, stream>>>(Wq, Wk, Wv, Wo, Wt, WoT);

  dim3 g1((B_SZ * LQ) / 64, 3);
  qkv_proj_mfma<<<g1, dim3(256), 0, stream>>>(ligand, pocket, bq, bk, bv, Wt,
                                              Qb, Kb, Vt);

  dim3 g2(LQ / QBLK, B_SZ);
  flash_attn_kernel<<<g2, dim3(256), 0, stream>>>(Qb, Kb, Vt, attnO);

  dim3 g3((B_SZ * LQ) / 64);
  out_proj_mfma<<<g3, dim3(256), 0, stream>>>(attnO, WoT, bo, out);
}

// Round 3
// 142.917 us; speedup vs baseline: 2.2075x; 1.3047x over previous
//
#include <hip/hip_runtime.h>

#define B_SZ 4
#define LQ 4096
#define LKV 4096
#define DIN 256
#define DOUT 128
#define QBLK 64
#define KVBLK 64
#define NT (LKV / KVBLK)
#define BLQ (B_SZ * LQ)

typedef unsigned short u16;
typedef __attribute__((ext_vector_type(8))) short bf16x8;
typedef __attribute__((ext_vector_type(4))) float f32x4;

union Bf8Pack {
  u16 u[8];
  bf16x8 v;
};
union U16x4Pack {
  u16 u[4];
  uint2 v;
};

__device__ __forceinline__ u16 f2bf(float x) {
  unsigned u = __float_as_uint(x);
  u += 0x7fffu + ((u >> 16) & 1u);
  return (u16)(u >> 16);
}

__device__ __forceinline__ void gload_lds16(const u16* g, u16* l) {
  __builtin_amdgcn_global_load_lds(
      (__attribute__((address_space(1))) unsigned int*)g,
      (__attribute__((address_space(3))) unsigned int*)l, 16, 0, 0);
}

// ---------- weight transpose + bf16 convert: Wt[3][128][256], WoT[128][128] ----------
__global__ __launch_bounds__(256) void wtrans_kernel(
    const float* __restrict__ Wq, const float* __restrict__ Wk,
    const float* __restrict__ Wv, const float* __restrict__ Wo,
    u16* __restrict__ Wt, u16* __restrict__ WoT) {
  const int gid = blockIdx.x * 256 + threadIdx.x;
  if (gid < 3 * DOUT * DIN) {
    const int which = gid / (DOUT * DIN);
    const int r = gid % (DOUT * DIN);
    const int n = r >> 8;
    const int k = r & 255;
    const float* W = (which == 0) ? Wq : (which == 1) ? Wk : Wv;
    Wt[gid] = f2bf(W[k * DOUT + n]);
  } else {
    const int r = gid - 3 * DOUT * DIN;
    if (r < DOUT * DOUT) {
      const int n = r >> 7;
      const int k = r & 127;
      WoT[r] = f2bf(Wo[k * DOUT + n]);
    }
  }
}

// ---------- QKV projection via MFMA ----------
__global__ __launch_bounds__(256) void qkv_proj_mfma(
    const float* __restrict__ ligand, const float* __restrict__ pocket,
    const float* __restrict__ bq, const float* __restrict__ bk,
    const float* __restrict__ bv, const u16* __restrict__ Wt,
    u16* __restrict__ Qb, u16* __restrict__ Kb, u16* __restrict__ Vt) {
  const int which = blockIdx.y;
  const int row0 = blockIdx.x * 64;
  const int tid = threadIdx.x;
  const int wid = tid >> 6;
  const int lane = tid & 63;
  const int lg = lane >> 4, lr = lane & 15;
  const float* __restrict__ src = (which == 0) ? ligand : pocket;
  const int m = row0 + wid * 16 + lr;

  bf16x8 sfrag[8];
#pragma unroll
  for (int ks = 0; ks < 8; ++ks) {
    const float* p = src + (size_t)m * DIN + ks * 32 + lg * 8;
    const float4 a = *(const float4*)p;
    const float4 b = *(const float4*)(p + 4);
    Bf8Pack pk;
    pk.u[0] = f2bf(a.x); pk.u[1] = f2bf(a.y); pk.u[2] = f2bf(a.z); pk.u[3] = f2bf(a.w);
    pk.u[4] = f2bf(b.x); pk.u[5] = f2bf(b.y); pk.u[6] = f2bf(b.z); pk.u[7] = f2bf(b.w);
    sfrag[ks] = pk.v;
  }

  const u16* __restrict__ Wtw = Wt + (size_t)which * DOUT * DIN;

  if (which < 2) {
    const float* __restrict__ bias = (which == 0) ? bq : bk;
    u16* __restrict__ dst = (which == 0) ? Qb : Kb;
#pragma unroll
    for (int dt = 0; dt < 8; ++dt) {
      f32x4 acc = (f32x4){0.f, 0.f, 0.f, 0.f};
#pragma unroll
      for (int ks = 0; ks < 8; ++ks) {
        const bf16x8 wf =
            *(const bf16x8*)(Wtw + (size_t)(dt * 16 + lr) * DIN + ks * 32 + lg * 8);
        acc = __builtin_amdgcn_mfma_f32_16x16x32_bf16(wf, sfrag[ks], acc, 0, 0, 0);
      }
      U16x4Pack st;
#pragma unroll
      for (int j = 0; j < 4; ++j) {
        const int d = dt * 16 + lg * 4 + j;
        float v = acc[j] + bias[d];
        if (which == 0) v *= 0.08838834764831845f;
        st.u[j] = f2bf(v);
      }
      *(uint2*)(dst + (size_t)m * DOUT + dt * 16 + lg * 4) = st.v;
    }
  } else {
    const int batch = row0 >> 12;
    const int kvbase = (row0 & 4095) + wid * 16 + lg * 4;
#pragma unroll
    for (int dt = 0; dt < 8; ++dt) {
      f32x4 acc = (f32x4){0.f, 0.f, 0.f, 0.f};
#pragma unroll
      for (int ks = 0; ks < 8; ++ks) {
        const bf16x8 wf =
            *(const bf16x8*)(Wtw + (size_t)(dt * 16 + lr) * DIN + ks * 32 + lg * 8);
        acc = __builtin_amdgcn_mfma_f32_16x16x32_bf16(sfrag[ks], wf, acc, 0, 0, 0);
      }
      const int d = dt * 16 + lr;
      const float b = bv[d];
      U16x4Pack st;
#pragma unroll
      for (int j = 0; j < 4; ++j) st.u[j] = f2bf(acc[j] + b);
      *(uint2*)(Vt + ((size_t)batch * DOUT + d) * LKV + kvbase) = st.v;
    }
  }
}

// ---------------- Flash attention (bf16 MFMA 16x16x32, KV-split) ----------------
__device__ __forceinline__ void stage_tiles(u16* KsB, u16* VsB,
                                            const u16* KbB, const u16* VtB,
                                            int t, int tid) {
#pragma unroll
  for (int i = 0; i < 4; ++i) {
    const int c = i * 256 + tid;
    const int r = c >> 4, ch = c & 15;
    const int chg = ch ^ (r & 7);
    gload_lds16(KbB + (size_t)(t * KVBLK + r) * 128 + chg * 8, KsB + (size_t)c * 8);
  }
#pragma unroll
  for (int i = 0; i < 4; ++i) {
    const int c = i * 256 + tid;
    const int d = c >> 3, ch = c & 7;
    const int chg = ch ^ (d & 7);
    gload_lds16(VtB + (size_t)d * LKV + (size_t)t * KVBLK + chg * 8,
                VsB + (size_t)c * 8);
  }
}

// mode 0: normalize + write bf16 attnO.  mode 1: fp32 unnormalized partial + Ml.
__global__ __launch_bounds__(256) void flash_attn_kernel(
    const u16* __restrict__ Qb, const u16* __restrict__ Kb,
    const u16* __restrict__ Vt, u16* __restrict__ attnO,
    float* __restrict__ Opart, float* __restrict__ Ml, int niter, int mode) {
  __shared__ __align__(16) u16 Ks[2][KVBLK * 128];
  __shared__ __align__(16) u16 Vs[2][128 * KVBLK];
  __shared__ __align__(16) u16 Ps[4][16 * 72];

  const int batch = blockIdx.y;
  const int split = blockIdx.z;
  const int q0 = blockIdx.x * QBLK;
  const int tid = threadIdx.x;
  const int wid = tid >> 6;
  const int lane = tid & 63;
  const int lg = lane >> 4;
  const int lr = lane & 15;
  const int t0 = split * niter;

  const u16* Qw = Qb + ((size_t)batch * LQ + q0 + wid * 16) * 128;
  const u16* KbB = Kb + (size_t)batch * LKV * 128;
  const u16* VtB = Vt + (size_t)batch * 128 * LKV;

  bf16x8 qf[4];
#pragma unroll
  for (int ks = 0; ks < 4; ++ks)
    qf[ks] = *(const bf16x8*)(Qw + (size_t)lr * 128 + ks * 32 + lg * 8);

  f32x4 oacc[8];
#pragma unroll
  for (int dt = 0; dt < 8; ++dt) oacc[dt] = (f32x4){0.f, 0.f, 0.f, 0.f};
  float m_run[4], l_run[4];
#pragma unroll
  for (int j = 0; j < 4; ++j) {
    m_run[j] = -1e30f;
    l_run[j] = 0.f;
  }

  stage_tiles(&Ks[0][0], &Vs[0][0], KbB, VtB, t0, tid);
  __syncthreads();

  int cur = 0;
  for (int ti = 0; ti < niter; ++ti) {
    if (ti + 1 < niter)
      stage_tiles(&Ks[cur ^ 1][0], &Vs[cur ^ 1][0], KbB, VtB, t0 + ti + 1, tid);

    const u16* KsB = &Ks[cur][0];
    const u16* VsB = &Vs[cur][0];

    f32x4 sacc[4];
#pragma unroll
    for (int ct = 0; ct < 4; ++ct) sacc[ct] = (f32x4){0.f, 0.f, 0.f, 0.f};
#pragma unroll
    for (int ks = 0; ks < 4; ++ks) {
#pragma unroll
      for (int ct = 0; ct < 4; ++ct) {
        const int r = ct * 16 + lr;
        const int ch = (ks * 4 + lg) ^ (r & 7);
        bf16x8 kf = *(const bf16x8*)(KsB + ((size_t)r * 16 + ch) * 8);
        sacc[ct] =
            __builtin_amdgcn_mfma_f32_16x16x32_bf16(qf[ks], kf, sacc[ct], 0, 0, 0);
      }
    }

    float pv[4][4];
    float corr[4];
#pragma unroll
    for (int j = 0; j < 4; ++j) {
      float mx = fmaxf(fmaxf(sacc[0][j], sacc[1][j]), fmaxf(sacc[2][j], sacc[3][j]));
#pragma unroll
      for (int s = 8; s >= 1; s >>= 1) mx = fmaxf(mx, __shfl_xor(mx, s, 64));
      const float mn = fmaxf(m_run[j], mx);
      corr[j] = __expf(m_run[j] - mn);
      m_run[j] = mn;
      float rs = 0.f;
#pragma unroll
      for (int ct = 0; ct < 4; ++ct) {
        const float p = __expf(sacc[ct][j] - mn);
        pv[ct][j] = p;
        rs += p;
      }
#pragma unroll
      for (int s = 8; s >= 1; s >>= 1) rs += __shfl_xor(rs, s, 64);
      l_run[j] = l_run[j] * corr[j] + rs;
    }

#pragma unroll
    for (int ct = 0; ct < 4; ++ct)
#pragma unroll
      for (int j = 0; j < 4; ++j)
        Ps[wid][(lg * 4 + j) * 72 + ct * 16 + lr] = f2bf(pv[ct][j]);

#pragma unroll
    for (int dt = 0; dt < 8; ++dt)
#pragma unroll
      for (int j = 0; j < 4; ++j) oacc[dt][j] *= corr[j];

#pragma unroll
    for (int ks2 = 0; ks2 < 2; ++ks2) {
      bf16x8 pf =
          *(const bf16x8*)(&Ps[wid][0] + (size_t)lr * 72 + ks2 * 32 + lg * 8);
#pragma unroll
      for (int dt = 0; dt < 8; ++dt) {
        const int d = dt * 16 + lr;
        const int ch = (ks2 * 4 + lg) ^ (d & 7);
        bf16x8 vf = *(const bf16x8*)(VsB + ((size_t)d * 8 + ch) * 8);
        oacc[dt] = __builtin_amdgcn_mfma_f32_16x16x32_bf16(pf, vf, oacc[dt], 0, 0, 0);
      }
    }
    __syncthreads();
    cur ^= 1;
  }

  if (mode == 0) {
    float rl[4];
#pragma unroll
    for (int j = 0; j < 4; ++j) rl[j] = 1.f / l_run[j];
    u16* O = attnO + ((size_t)batch * LQ + q0 + wid * 16) * 128;
#pragma unroll
    for (int dt = 0; dt < 8; ++dt)
#pragma unroll
      for (int j = 0; j < 4; ++j)
        O[(size_t)(lg * 4 + j) * 128 + dt * 16 + lr] = f2bf(oacc[dt][j] * rl[j]);
  } else {
    const size_t rowbase = (size_t)split * BLQ + (size_t)batch * LQ + q0 + wid * 16;
    float* Op = Opart + rowbase * 128;
#pragma unroll
    for (int dt = 0; dt < 8; ++dt)
#pragma unroll
      for (int j = 0; j < 4; ++j)
        Op[(size_t)(lg * 4 + j) * 128 + dt * 16 + lr] = oacc[dt][j];
    if (lr == 0) {
#pragma unroll
      for (int j = 0; j < 4; ++j) {
        Ml[(rowbase + lg * 4 + j) * 2 + 0] = m_run[j];
        Ml[(rowbase + lg * 4 + j) * 2 + 1] = l_run[j];
      }
    }
  }
}

// ---------- combine KV-splits + output projection via MFMA ----------
// grid BLQ/64, block 256
__global__ __launch_bounds__(256) void combine_out_proj(
    const float* __restrict__ Opart, const float* __restrict__ Ml,
    const u16* __restrict__ WoT, const float* __restrict__ bo,
    float* __restrict__ out, int nsplit) {
  const int row0 = blockIdx.x * 64;
  const int tid = threadIdx.x;
  const int wid = tid >> 6;
  const int lane = tid & 63;
  const int lg = lane >> 4, lr = lane & 15;
  const int m = row0 + wid * 16 + lr;

  const float m0 = Ml[(size_t)m * 2 + 0];
  const float l0 = Ml[(size_t)m * 2 + 1];
  float m1 = -1e30f, l1 = 0.f;
  if (nsplit == 2) {
    m1 = Ml[((size_t)BLQ + m) * 2 + 0];
    l1 = Ml[((size_t)BLQ + m) * 2 + 1];
  }
  const float M = fmaxf(m0, m1);
  float e0 = __expf(m0 - M);
  float e1 = (nsplit == 2) ? __expf(m1 - M) : 0.f;
  const float inv = 1.f / (l0 * e0 + l1 * e1);
  e0 *= inv;
  e1 *= inv;

  bf16x8 ofrag[4];
#pragma unroll
  for (int ks = 0; ks < 4; ++ks) {
    const float* p0 = Opart + (size_t)m * 128 + ks * 32 + lg * 8;
    const float4 a = *(const float4*)p0;
    const float4 b = *(const float4*)(p0 + 4);
    float4 c = {0, 0, 0, 0}, d = {0, 0, 0, 0};
    if (nsplit == 2) {
      const float* p1 = p0 + (size_t)BLQ * 128;
      c = *(const float4*)p1;
      d = *(const float4*)(p1 + 4);
    }
    Bf8Pack pk;
    pk.u[0] = f2bf(e0 * a.x + e1 * c.x);
    pk.u[1] = f2bf(e0 * a.y + e1 * c.y);
    pk.u[2] = f2bf(e0 * a.z + e1 * c.z);
    pk.u[3] = f2bf(e0 * a.w + e1 * c.w);
    pk.u[4] = f2bf(e0 * b.x + e1 * d.x);
    pk.u[5] = f2bf(e0 * b.y + e1 * d.y);
    pk.u[6] = f2bf(e0 * b.z + e1 * d.z);
    pk.u[7] = f2bf(e0 * b.w + e1 * d.w);
    ofrag[ks] = pk.v;
  }

#pragma unroll
  for (int dt = 0; dt < 8; ++dt) {
    f32x4 acc = (f32x4){0.f, 0.f, 0.f, 0.f};
#pragma unroll
    for (int ks = 0; ks < 4; ++ks) {
      const bf16x8 wf =
          *(const bf16x8*)(WoT + (size_t)(dt * 16 + lr) * DOUT + ks * 32 + lg * 8);
      acc = __builtin_amdgcn_mfma_f32_16x16x32_bf16(wf, ofrag[ks], acc, 0, 0, 0);
    }
    float4 o;
    o.x = acc[0] + bo[dt * 16 + lg * 4 + 0];
    o.y = acc[1] + bo[dt * 16 + lg * 4 + 1];
    o.z = acc[2] + bo[dt * 16 + lg * 4 + 2];
    o.w = acc[3] + bo[dt * 16 + lg * 4 + 3];
    *(float4*)(out + (size_t)m * DOUT + dt * 16 + lg * 4) = o;
  }
}

// ---------- output projection via MFMA (compact fallback, mode 0) ----------
__global__ __launch_bounds__(256) void out_proj_mfma(
    const u16* __restrict__ attnO, const u16* __restrict__ WoT,
    const float* __restrict__ bo, float* __restrict__ out) {
  const int row0 = blockIdx.x * 64;
  const int tid = threadIdx.x;
  const int wid = tid >> 6;
  const int lane = tid & 63;
  const int lg = lane >> 4, lr = lane & 15;
  const int m = row0 + wid * 16 + lr;

  bf16x8 ofrag[4];
#pragma unroll
  for (int ks = 0; ks < 4; ++ks)
    ofrag[ks] = *(const bf16x8*)(attnO + (size_t)m * DOUT + ks * 32 + lg * 8);

#pragma unroll
  for (int dt = 0; dt < 8; ++dt) {
    f32x4 acc = (f32x4){0.f, 0.f, 0.f, 0.f};
#pragma unroll
    for (int ks = 0; ks < 4; ++ks) {
      const bf16x8 wf =
          *(const bf16x8*)(WoT + (size_t)(dt * 16 + lr) * DOUT + ks * 32 + lg * 8);
      acc = __builtin_amdgcn_mfma_f32_16x16x32_bf16(wf, ofrag[ks], acc, 0, 0, 0);
    }
    float4 o;
    o.x = acc[0] + bo[dt * 16 + lg * 4 + 0];
    o.y = acc[1] + bo[dt * 16 + lg * 4 + 1];
    o.z = acc[2] + bo[dt * 16 + lg * 4 + 2];
    o.w = acc[3] + bo[dt * 16 + lg * 4 + 3];
    *(float4*)(out + (size_t)m * DOUT + dt * 16 + lg * 4) = o;
  }
}

extern "C" void kernel_launch(void* const* d_in, const int* in_sizes, int n_in,
                              void* d_out, int out_size, void* d_ws,
                              size_t ws_size, hipStream_t stream) {
  const float* ligand = (const float*)d_in[0];
  const float* pocket = (const float*)d_in[1];
  const float* Wq = (const float*)d_in[2];
  const float* bq = (const float*)d_in[3];
  const float* Wk = (const float*)d_in[4];
  const float* bk = (const float*)d_in[5];
  const float* Wv = (const float*)d_in[6];
  const float* bv = (const float*)d_in[7];
  const float* Wo = (const float*)d_in[8];
  const float* bo = (const float*)d_in[9];
  float* out = (float*)d_out;

  const size_t MB = 1024 * 1024;
  char* ws = (char*)d_ws;
  u16* Qb = (u16*)(ws);
  u16* Kb = (u16*)(ws + 4 * MB);
  u16* Vt = (u16*)(ws + 8 * MB);

  int ns, mode;
  if (ws_size >= 31 * MB) {
    ns = 2; mode = 1;
  } else if (ws_size >= 23 * MB) {
    ns = 1; mode = 1;
  } else {
    ns = 1; mode = 0;
  }

  u16 *Wt, *WoT, *attnO = nullptr;
  float *Opart = nullptr, *Ml = nullptr;
  if (mode == 1) {
    Wt = (u16*)(ws + 12 * MB);
    WoT = Wt + 3 * DOUT * DIN;
    Opart = (float*)(ws + 13 * MB);
    Ml = (float*)(ws + 13 * MB + (size_t)ns * 8 * MB);
  } else {
    attnO = (u16*)(ws + 12 * MB);
    Wt = (u16*)(ws + 16 * MB);
    WoT = Wt + 3 * DOUT * DIN;
  }

  wtrans_kernel<<<dim3(448), dim3(256), 0, stream>>>(Wq, Wk, Wv, Wo, Wt, WoT);

  dim3 g1(BLQ / 64, 3);
  qkv_proj_mfma<<<g1, dim3(256), 0, stream>>>(ligand, pocket, bq, bk, bv, Wt,
                                              Qb, Kb, Vt);

  dim3 g2(LQ / QBLK, B_SZ, ns);
  flash_attn_kernel<<<g2, dim3(256), 0, stream>>>(Qb, Kb, Vt, attnO, Opart, Ml,
                                                  NT / ns, mode);

  dim3 g3(BLQ / 64);
  if (mode == 1) {
    combine_out_proj<<<g3, dim3(256), 0, stream>>>(Opart, Ml, WoT, bo, out, ns);
  } else {
    out_proj_mfma<<<g3, dim3(256), 0, stream>>>(attnO, WoT, bo, out);
  }
}

// Round 4
// 123.763 us; speedup vs baseline: 2.5492x; 1.1548x over previous
//
#include <hip/hip_runtime.h>

#define B_SZ 4
#define LQ 4096
#define LKV 4096
#define DIN 256
#define DOUT 128
#define QBLK 64
#define KVBLK 64
#define NT (LKV / KVBLK)
#define BLQ (B_SZ * LQ)

typedef unsigned short u16;
typedef __attribute__((ext_vector_type(8))) short bf16x8;
typedef __attribute__((ext_vector_type(4))) float f32x4;

union Bf8Pack {
  u16 u[8];
  bf16x8 v;
};
union U16x4Pack {
  u16 u[4];
  uint2 v;
};

__device__ __forceinline__ u16 f2bf(float x) {
  unsigned u = __float_as_uint(x);
  u += 0x7fffu + ((u >> 16) & 1u);
  return (u16)(u >> 16);
}

__device__ __forceinline__ unsigned cvt_pk_bf16(float lo, float hi) {
  unsigned r;
  asm("v_cvt_pk_bf16_f32 %0, %1, %2" : "=v"(r) : "v"(lo), "v"(hi));
  return r;
}

__device__ __forceinline__ void gload_lds16(const u16* g, u16* l) {
  __builtin_amdgcn_global_load_lds(
      (__attribute__((address_space(1))) unsigned int*)g,
      (__attribute__((address_space(3))) unsigned int*)l, 16, 0, 0);
}

// ---------- weight transpose + bf16 convert: Wt[3][128][256], WoT[128][128] ----------
__global__ __launch_bounds__(256) void wtrans_kernel(
    const float* __restrict__ Wq, const float* __restrict__ Wk,
    const float* __restrict__ Wv, const float* __restrict__ Wo,
    u16* __restrict__ Wt, u16* __restrict__ WoT) {
  const int gid = blockIdx.x * 256 + threadIdx.x;
  if (gid < 3 * DOUT * DIN) {
    const int which = gid / (DOUT * DIN);
    const int r = gid % (DOUT * DIN);
    const int n = r >> 8;
    const int k = r & 255;
    const float* W = (which == 0) ? Wq : (which == 1) ? Wk : Wv;
    Wt[gid] = f2bf(W[k * DOUT + n]);
  } else {
    const int r = gid - 3 * DOUT * DIN;
    if (r < DOUT * DOUT) {
      const int n = r >> 7;
      const int k = r & 127;
      WoT[r] = f2bf(Wo[k * DOUT + n]);
    }
  }
}

// ---------- QKV projection via MFMA ----------
__global__ __launch_bounds__(256) void qkv_proj_mfma(
    const float* __restrict__ ligand, const float* __restrict__ pocket,
    const float* __restrict__ bq, const float* __restrict__ bk,
    const float* __restrict__ bv, const u16* __restrict__ Wt,
    u16* __restrict__ Qb, u16* __restrict__ Kb, u16* __restrict__ Vt) {
  const int which = blockIdx.y;
  const int row0 = blockIdx.x * 64;
  const int tid = threadIdx.x;
  const int wid = tid >> 6;
  const int lane = tid & 63;
  const int lg = lane >> 4, lr = lane & 15;
  const float* __restrict__ src = (which == 0) ? ligand : pocket;
  const int m = row0 + wid * 16 + lr;

  bf16x8 sfrag[8];
#pragma unroll
  for (int ks = 0; ks < 8; ++ks) {
    const float* p = src + (size_t)m * DIN + ks * 32 + lg * 8;
    const float4 a = *(const float4*)p;
    const float4 b = *(const float4*)(p + 4);
    Bf8Pack pk;
    pk.u[0] = f2bf(a.x); pk.u[1] = f2bf(a.y); pk.u[2] = f2bf(a.z); pk.u[3] = f2bf(a.w);
    pk.u[4] = f2bf(b.x); pk.u[5] = f2bf(b.y); pk.u[6] = f2bf(b.z); pk.u[7] = f2bf(b.w);
    sfrag[ks] = pk.v;
  }

  const u16* __restrict__ Wtw = Wt + (size_t)which * DOUT * DIN;

  if (which < 2) {
    const float* __restrict__ bias = (which == 0) ? bq : bk;
    u16* __restrict__ dst = (which == 0) ? Qb : Kb;
    // Q is pre-scaled by 1/sqrt(128) * log2(e) so flash can use exp2 directly.
    const float qscale = (float)(0.08838834764831845 * 1.4426950408889634);
#pragma unroll
    for (int dt = 0; dt < 8; ++dt) {
      f32x4 acc = (f32x4){0.f, 0.f, 0.f, 0.f};
#pragma unroll
      for (int ks = 0; ks < 8; ++ks) {
        const bf16x8 wf =
            *(const bf16x8*)(Wtw + (size_t)(dt * 16 + lr) * DIN + ks * 32 + lg * 8);
        acc = __builtin_amdgcn_mfma_f32_16x16x32_bf16(wf, sfrag[ks], acc, 0, 0, 0);
      }
      U16x4Pack st;
#pragma unroll
      for (int j = 0; j < 4; ++j) {
        const int d = dt * 16 + lg * 4 + j;
        float v = acc[j] + bias[d];
        if (which == 0) v *= qscale;
        st.u[j] = f2bf(v);
      }
      *(uint2*)(dst + (size_t)m * DOUT + dt * 16 + lg * 4) = st.v;
    }
  } else {
    const int batch = row0 >> 12;
    const int kvbase = (row0 & 4095) + wid * 16 + lg * 4;
#pragma unroll
    for (int dt = 0; dt < 8; ++dt) {
      f32x4 acc = (f32x4){0.f, 0.f, 0.f, 0.f};
#pragma unroll
      for (int ks = 0; ks < 8; ++ks) {
        const bf16x8 wf =
            *(const bf16x8*)(Wtw + (size_t)(dt * 16 + lr) * DIN + ks * 32 + lg * 8);
        acc = __builtin_amdgcn_mfma_f32_16x16x32_bf16(sfrag[ks], wf, acc, 0, 0, 0);
      }
      const int d = dt * 16 + lr;
      const float b = bv[d];
      U16x4Pack st;
#pragma unroll
      for (int j = 0; j < 4; ++j) st.u[j] = f2bf(acc[j] + b);
      *(uint2*)(Vt + ((size_t)batch * DOUT + d) * LKV + kvbase) = st.v;
    }
  }
}

// ---------------- Flash attention (swapped-operand, in-register softmax) ----------------
__device__ __forceinline__ void stage_tiles(u16* KsB, u16* VsB,
                                            const u16* KbB, const u16* VtB,
                                            int t, int tid) {
#pragma unroll
  for (int i = 0; i < 4; ++i) {
    const int c = i * 256 + tid;
    const int r = c >> 4, ch = c & 15;
    const int chg = ch ^ (r & 7);
    gload_lds16(KbB + (size_t)(t * KVBLK + r) * 128 + chg * 8, KsB + (size_t)c * 8);
  }
#pragma unroll
  for (int i = 0; i < 4; ++i) {
    const int c = i * 256 + tid;
    const int d = c >> 3, ch = c & 7;
    const int chg = ch ^ (d & 7);
    gload_lds16(VtB + (size_t)d * LKV + (size_t)t * KVBLK + chg * 8,
                VsB + (size_t)c * 8);
  }
}

// mode 0: normalize + write bf16 attnO.  mode 1: fp32 unnormalized partial + Ml.
__global__ __launch_bounds__(256) void flash_attn_kernel(
    const u16* __restrict__ Qb, const u16* __restrict__ Kb,
    const u16* __restrict__ Vt, u16* __restrict__ attnO,
    float* __restrict__ Opart, float* __restrict__ Ml, int niter, int mode) {
  __shared__ __align__(16) u16 Ks[2][KVBLK * 128];
  __shared__ __align__(16) u16 Vs[2][128 * KVBLK];
  __shared__ __align__(16) unsigned Psw[4][16 * 32];  // per-wave P^ (bf16 pairs), XOR-swizzled

  const int batch = blockIdx.y;
  const int split = blockIdx.z;
  const int q0 = blockIdx.x * QBLK;
  const int tid = threadIdx.x;
  const int wid = tid >> 6;
  const int lane = tid & 63;
  const int lg = lane >> 4;
  const int lr = lane & 15;
  const int sw = (lr & 7) << 2;  // LDS word-col swizzle for this lane's q-row
  const int t0 = split * niter;

  const u16* Qw = Qb + ((size_t)batch * LQ + q0 + wid * 16) * 128;
  const u16* KbB = Kb + (size_t)batch * LKV * 128;
  const u16* VtB = Vt + (size_t)batch * 128 * LKV;

  // Q as B-frag: lane holds Q[q=lr][ks*32 + lg*8 .. +8]
  bf16x8 qf[4];
#pragma unroll
  for (int ks = 0; ks < 4; ++ks)
    qf[ks] = *(const bf16x8*)(Qw + (size_t)lr * 128 + ks * 32 + lg * 8);

  // O^T accumulator: lane holds O[q=lr][d = dt*16 + lg*4 + j]
  f32x4 oacc[8];
#pragma unroll
  for (int dt = 0; dt < 8; ++dt) oacc[dt] = (f32x4){0.f, 0.f, 0.f, 0.f};
  float m_run = -1e30f, l_run = 0.f;  // per-lane scalars (one q-row each)

  stage_tiles(&Ks[0][0], &Vs[0][0], KbB, VtB, t0, tid);
  __syncthreads();

  int cur = 0;
  for (int ti = 0; ti < niter; ++ti) {
    if (ti + 1 < niter)
      stage_tiles(&Ks[cur ^ 1][0], &Vs[cur ^ 1][0], KbB, VtB, t0 + ti + 1, tid);

    const u16* KsB = &Ks[cur][0];
    const u16* VsB = &Vs[cur][0];

    // S^T = K Q^T per wave: sacc[ct] holds S[q=lr][kv = ct*16 + lg*4 + j]
    f32x4 sacc[4];
#pragma unroll
    for (int ct = 0; ct < 4; ++ct) sacc[ct] = (f32x4){0.f, 0.f, 0.f, 0.f};
#pragma unroll
    for (int ks = 0; ks < 4; ++ks) {
#pragma unroll
      for (int ct = 0; ct < 4; ++ct) {
        const int r = ct * 16 + lr;
        const int ch = (ks * 4 + lg) ^ (r & 7);
        bf16x8 kf = *(const bf16x8*)(KsB + ((size_t)r * 16 + ch) * 8);
        sacc[ct] =
            __builtin_amdgcn_mfma_f32_16x16x32_bf16(kf, qf[ks], sacc[ct], 0, 0, 0);
      }
    }

    // in-register row softmax (row is lane-local across 16 regs + lanes +-16/32)
    float mx = fmaxf(fmaxf(sacc[0][0], sacc[0][1]), fmaxf(sacc[0][2], sacc[0][3]));
#pragma unroll
    for (int ct = 1; ct < 4; ++ct)
      mx = fmaxf(mx, fmaxf(fmaxf(sacc[ct][0], sacc[ct][1]),
                           fmaxf(sacc[ct][2], sacc[ct][3])));
    mx = fmaxf(mx, __shfl_xor(mx, 16, 64));
    mx = fmaxf(mx, __shfl_xor(mx, 32, 64));

    // defer-max: only rescale when the wave saw meaningful growth (log2 domain)
    if (!__all(mx - m_run <= 11.5f)) {
      const float mn = fmaxf(m_run, mx);
      const float corr = exp2f(m_run - mn);
      m_run = mn;
      l_run *= corr;
#pragma unroll
      for (int dt = 0; dt < 8; ++dt)
#pragma unroll
        for (int j = 0; j < 4; ++j) oacc[dt][j] *= corr;
    }

    float rs = 0.f;
    unsigned pw0[4], pw1[4];
#pragma unroll
    for (int ct = 0; ct < 4; ++ct) {
      const float p0 = exp2f(sacc[ct][0] - m_run);
      const float p1 = exp2f(sacc[ct][1] - m_run);
      const float p2 = exp2f(sacc[ct][2] - m_run);
      const float p3 = exp2f(sacc[ct][3] - m_run);
      rs += (p0 + p1) + (p2 + p3);
      pw0[ct] = cvt_pk_bf16(p0, p1);
      pw1[ct] = cvt_pk_bf16(p2, p3);
    }
    rs += __shfl_xor(rs, 16, 64);
    rs += __shfl_xor(rs, 32, 64);
    l_run += rs;

    // store P pairs to swizzled per-wave tile: row q=lr, word col = kv/2
    unsigned* Pw = &Psw[wid][lr * 32];
#pragma unroll
    for (int ct = 0; ct < 4; ++ct) {
      Pw[(ct * 8 + lg * 2 + 0) ^ sw] = pw0[ct];
      Pw[(ct * 8 + lg * 2 + 1) ^ sw] = pw1[ct];
    }

    // O^T += V^T P^T : A = V^T rows d, B = P rows q
#pragma unroll
    for (int ks2 = 0; ks2 < 2; ++ks2) {
      const bf16x8 pf =
          *(const bf16x8*)&Psw[wid][lr * 32 + ((ks2 * 16 + lg * 4) ^ sw)];
#pragma unroll
      for (int dt = 0; dt < 8; ++dt) {
        const int d = dt * 16 + lr;
        const int ch = (ks2 * 4 + lg) ^ (d & 7);
        bf16x8 vf = *(const bf16x8*)(VsB + ((size_t)d * 8 + ch) * 8);
        oacc[dt] = __builtin_amdgcn_mfma_f32_16x16x32_bf16(vf, pf, oacc[dt], 0, 0, 0);
      }
    }
    __syncthreads();
    cur ^= 1;
  }

  if (mode == 0) {
    const float rl = 1.f / l_run;
    u16* O = attnO + ((size_t)batch * LQ + q0 + wid * 16 + lr) * 128;
#pragma unroll
    for (int dt = 0; dt < 8; ++dt) {
      uint2 st;
      st.x = cvt_pk_bf16(oacc[dt][0] * rl, oacc[dt][1] * rl);
      st.y = cvt_pk_bf16(oacc[dt][2] * rl, oacc[dt][3] * rl);
      *(uint2*)(O + dt * 16 + lg * 4) = st;
    }
  } else {
    const size_t rowbase = (size_t)split * BLQ + (size_t)batch * LQ + q0 + wid * 16;
    float* Op = Opart + (rowbase + lr) * 128;
#pragma unroll
    for (int dt = 0; dt < 8; ++dt) {
      float4 o = {oacc[dt][0], oacc[dt][1], oacc[dt][2], oacc[dt][3]};
      *(float4*)(Op + dt * 16 + lg * 4) = o;
    }
    if (lane < 16) {
      Ml[(rowbase + lr) * 2 + 0] = m_run;
      Ml[(rowbase + lr) * 2 + 1] = l_run;
    }
  }
}

// ---------- combine KV-splits + output projection via MFMA ----------
__global__ __launch_bounds__(256) void combine_out_proj(
    const float* __restrict__ Opart, const float* __restrict__ Ml,
    const u16* __restrict__ WoT, const float* __restrict__ bo,
    float* __restrict__ out, int nsplit) {
  const int row0 = blockIdx.x * 64;
  const int tid = threadIdx.x;
  const int wid = tid >> 6;
  const int lane = tid & 63;
  const int lg = lane >> 4, lr = lane & 15;
  const int m = row0 + wid * 16 + lr;

  const float m0 = Ml[(size_t)m * 2 + 0];
  const float l0 = Ml[(size_t)m * 2 + 1];
  float m1 = -1e30f, l1 = 0.f;
  if (nsplit == 2) {
    m1 = Ml[((size_t)BLQ + m) * 2 + 0];
    l1 = Ml[((size_t)BLQ + m) * 2 + 1];
  }
  const float M = fmaxf(m0, m1);
  float e0 = exp2f(m0 - M);  // m values live in log2 domain
  float e1 = (nsplit == 2) ? exp2f(m1 - M) : 0.f;
  const float inv = 1.f / (l0 * e0 + l1 * e1);
  e0 *= inv;
  e1 *= inv;

  bf16x8 ofrag[4];
#pragma unroll
  for (int ks = 0; ks < 4; ++ks) {
    const float* p0 = Opart + (size_t)m * 128 + ks * 32 + lg * 8;
    const float4 a = *(const float4*)p0;
    const float4 b = *(const float4*)(p0 + 4);
    float4 c = {0, 0, 0, 0}, d = {0, 0, 0, 0};
    if (nsplit == 2) {
      const float* p1 = p0 + (size_t)BLQ * 128;
      c = *(const float4*)p1;
      d = *(const float4*)(p1 + 4);
    }
    Bf8Pack pk;
    pk.u[0] = f2bf(e0 * a.x + e1 * c.x);
    pk.u[1] = f2bf(e0 * a.y + e1 * c.y);
    pk.u[2] = f2bf(e0 * a.z + e1 * c.z);
    pk.u[3] = f2bf(e0 * a.w + e1 * c.w);
    pk.u[4] = f2bf(e0 * b.x + e1 * d.x);
    pk.u[5] = f2bf(e0 * b.y + e1 * d.y);
    pk.u[6] = f2bf(e0 * b.z + e1 * d.z);
    pk.u[7] = f2bf(e0 * b.w + e1 * d.w);
    ofrag[ks] = pk.v;
  }

#pragma unroll
  for (int dt = 0; dt < 8; ++dt) {
    f32x4 acc = (f32x4){0.f, 0.f, 0.f, 0.f};
#pragma unroll
    for (int ks = 0; ks < 4; ++ks) {
      const bf16x8 wf =
          *(const bf16x8*)(WoT + (size_t)(dt * 16 + lr) * DOUT + ks * 32 + lg * 8);
      acc = __builtin_amdgcn_mfma_f32_16x16x32_bf16(wf, ofrag[ks], acc, 0, 0, 0);
    }
    float4 o;
    o.x = acc[0] + bo[dt * 16 + lg * 4 + 0];
    o.y = acc[1] + bo[dt * 16 + lg * 4 + 1];
    o.z = acc[2] + bo[dt * 16 + lg * 4 + 2];
    o.w = acc[3] + bo[dt * 16 + lg * 4 + 3];
    *(float4*)(out + (size_t)m * DOUT + dt * 16 + lg * 4) = o;
  }
}

// ---------- output projection via MFMA (fallback, mode 0) ----------
__global__ __launch_bounds__(256) void out_proj_mfma(
    const u16* __restrict__ attnO, const u16* __restrict__ WoT,
    const float* __restrict__ bo, float* __restrict__ out) {
  const int row0 = blockIdx.x * 64;
  const int tid = threadIdx.x;
  const int wid = tid >> 6;
  const int lane = tid & 63;
  const int lg = lane >> 4, lr = lane & 15;
  const int m = row0 + wid * 16 + lr;

  bf16x8 ofrag[4];
#pragma unroll
  for (int ks = 0; ks < 4; ++ks)
    ofrag[ks] = *(const bf16x8*)(attnO + (size_t)m * DOUT + ks * 32 + lg * 8);

#pragma unroll
  for (int dt = 0; dt < 8; ++dt) {
    f32x4 acc = (f32x4){0.f, 0.f, 0.f, 0.f};
#pragma unroll
    for (int ks = 0; ks < 4; ++ks) {
      const bf16x8 wf =
          *(const bf16x8*)(WoT + (size_t)(dt * 16 + lr) * DOUT + ks * 32 + lg * 8);
      acc = __builtin_amdgcn_mfma_f32_16x16x32_bf16(wf, ofrag[ks], acc, 0, 0, 0);
    }
    float4 o;
    o.x = acc[0] + bo[dt * 16 + lg * 4 + 0];
    o.y = acc[1] + bo[dt * 16 + lg * 4 + 1];
    o.z = acc[2] + bo[dt * 16 + lg * 4 + 2];
    o.w = acc[3] + bo[dt * 16 + lg * 4 + 3];
    *(float4*)(out + (size_t)m * DOUT + dt * 16 + lg * 4) = o;
  }
}

extern "C" void kernel_launch(void* const* d_in, const int* in_sizes, int n_in,
                              void* d_out, int out_size, void* d_ws,
                              size_t ws_size, hipStream_t stream) {
  const float* ligand = (const float*)d_in[0];
  const float* pocket = (const float*)d_in[1];
  const float* Wq = (const float*)d_in[2];
  const float* bq = (const float*)d_in[3];
  const float* Wk = (const float*)d_in[4];
  const float* bk = (const float*)d_in[5];
  const float* Wv = (const float*)d_in[6];
  const float* bv = (const float*)d_in[7];
  const float* Wo = (const float*)d_in[8];
  const float* bo = (const float*)d_in[9];
  float* out = (float*)d_out;

  const size_t MB = 1024 * 1024;
  char* ws = (char*)d_ws;
  u16* Qb = (u16*)(ws);
  u16* Kb = (u16*)(ws + 4 * MB);
  u16* Vt = (u16*)(ws + 8 * MB);

  int ns, mode;
  if (ws_size >= 31 * MB) {
    ns = 2; mode = 1;
  } else if (ws_size >= 23 * MB) {
    ns = 1; mode = 1;
  } else {
    ns = 1; mode = 0;
  }

  u16 *Wt, *WoT, *attnO = nullptr;
  float *Opart = nullptr, *Ml = nullptr;
  if (mode == 1) {
    Wt = (u16*)(ws + 12 * MB);
    WoT = Wt + 3 * DOUT * DIN;
    Opart = (float*)(ws + 13 * MB);
    Ml = (float*)(ws + 13 * MB + (size_t)ns * 8 * MB);
  } else {
    attnO = (u16*)(ws + 12 * MB);
    Wt = (u16*)(ws + 16 * MB);
    WoT = Wt + 3 * DOUT * DIN;
  }

  wtrans_kernel<<<dim3(448), dim3(256), 0, stream>>>(Wq, Wk, Wv, Wo, Wt, WoT);

  dim3 g1(BLQ / 64, 3);
  qkv_proj_mfma<<<g1, dim3(256), 0, stream>>>(ligand, pocket, bq, bk, bv, Wt,
                                              Qb, Kb, Vt);

  dim3 g2(LQ / QBLK, B_SZ, ns);
  flash_attn_kernel<<<g2, dim3(256), 0, stream>>>(Qb, Kb, Vt, attnO, Opart, Ml,
                                                  NT / ns, mode);

  dim3 g3(BLQ / 64);
  if (mode == 1) {
    combine_out_proj<<<g3, dim3(256), 0, stream>>>(Opart, Ml, WoT, bo, out, ns);
  } else {
    out_proj_mfma<<<g3, dim3(256), 0, stream>>>(attnO, WoT, bo, out);
  }
}